// Round 6
// baseline (326.406 us; speedup 1.0000x reference)
//
#include <hip/hip_runtime.h>
#include <math.h>

#define NN 512
#define SD 32
#define HM 64
#define NB 256   // grid blocks = CU count; 1 block/CU (LDS-limited) => co-resident (proven R4/R5)

typedef _Float16 f16x8 __attribute__((ext_vector_type(8)));
typedef float floatx4 __attribute__((ext_vector_type(4)));
typedef unsigned uintx4 __attribute__((ext_vector_type(4)));

// ---- dynamic LDS layout (bytes) ----
#define OFF_HBS   0        // 512 rows x 144 B packed-f16 hip        = 73728
#define OFF_M2L   73728    // 8 waves x 2304 B                       = 18432
#define OFF_MSUM  92160    // 8x32 f32
#define OFF_HPREV 93184    // 2x32 f32
#define OFF_HS    93440    // 2x32 f32
#define OFF_MSG   93696    // 2x32 f32
#define OFF_GI    93952    // 2x96 f32
#define OFF_GH    94720    // 2x96 f32
#define OFF_HJ    95488    // 2 nodes x 128 B packed-f16 hj          = 256
#define OFF_W1T   95744    // 67x65 f32 (pad 65)                     = 17420
#define OFF_WIH   113168   // 64x97 f32 ([k][r], pad 97)             = 24832
#define OFF_WHH   138000   // 32x97 f32 ([k][r], pad 97)             = 12416
#define LDS_TOTAL 150416   // < 160 KiB/CU

// hb buffers spaced 128 KB apart (32768 dwords) so no adjacent-line/sector
// effect during step t's cached staging can pull step t+1's lines into an
// L2 before their sc1 stores land.
#define HB_STRIDE 32768

__device__ __forceinline__ float sigmoidf_(float x) {
    return 1.0f / (1.0f + __expf(-x));
}
__device__ __forceinline__ unsigned pkrtz(float a, float b) {
    unsigned r;
    asm("v_cvt_pkrtz_f16_f32 %0, %1, %2" : "=v"(r) : "v"(a), "v"(b));
    return r;
}
__device__ __forceinline__ unsigned pk_add(unsigned a, unsigned b) {
    unsigned r;
    asm("v_pk_add_f16 %0, %1, %2" : "=v"(r) : "v"(a), "v"(b));
    return r;
}
__device__ __forceinline__ unsigned pk_fma(unsigned a, unsigned b, unsigned c) {
    unsigned r;
    asm("v_pk_fma_f16 %0, %1, %2, %3" : "=v"(r) : "v"(a), "v"(b), "v"(c));
    return r;
}
__device__ __forceinline__ unsigned pk_relu(unsigned a) {
    unsigned r, z = 0u;
    asm("v_pk_max_f16 %0, %1, %2" : "=v"(r) : "v"(a), "v"(z));
    return r;
}

// ---------------------------------------------------------------------------
// Grid barrier (identical to R5 — kept fixed this round to isolate the
// staging-read change): 2-level arrival tree on separate 128 B lines,
// release via a single read-mostly 'rdy' word. RELAXED sc1 point-ops only;
// no agent acquire/release fences (R2: those writeback/invalidate whole L2s).
// __syncthreads() before arrival drains vmcnt so this block's sc1 stores
// are at L3 before its count bumps. Verified R3/R4/R5 (absmax 0.0).
// ---------------------------------------------------------------------------
__device__ __forceinline__ void grid_bar(unsigned* bar, int bi)
{
    __syncthreads();
    if (threadIdx.x == 0) {
        unsigned* cg = bar + (bi * 16 + ((int)blockIdx.x >> 5)) * 32;
        unsigned old = __hip_atomic_fetch_add(cg, 1u, __ATOMIC_RELAXED,
                                              __HIP_MEMORY_SCOPE_AGENT);
        if (old == 31u) {
            unsigned* cr = bar + (bi * 16 + 8) * 32;
            unsigned o2 = __hip_atomic_fetch_add(cr, 1u, __ATOMIC_RELAXED,
                                                 __HIP_MEMORY_SCOPE_AGENT);
            if (o2 == 7u)
                __hip_atomic_store(bar + 4096, (unsigned)(bi + 1),
                                   __ATOMIC_RELAXED, __HIP_MEMORY_SCOPE_AGENT);
        }
        while (__hip_atomic_load(bar + 4096, __ATOMIC_RELAXED,
                                 __HIP_MEMORY_SCOPE_AGENT) < (unsigned)(bi + 1))
            __builtin_amdgcn_s_sleep(16);
        (void)__hip_atomic_load(bar + 4096, __ATOMIC_ACQUIRE,
                                __HIP_MEMORY_SCOPE_AGENT);
    }
    __syncthreads();
}

// ===========================================================================
// Persistent fused kernel v5. Coherence protocol for hb (the only
// cross-block state):
//   WRITE: sc1 write-through atomic stores (fresh data lands below L2).
//   READ:  normal CACHED loads. Safe because kernel-begin acquire
//          invalidated all L2s, and each hb buffer is touched only by sc1
//          stores until after its barrier -> first cached read MUST miss L2
//          and fill with the fresh value; then ~31 sibling blocks per XCD
//          hit L2. (R5's sc1 point-reads made every one of 4096 x 16 B
//          staging loads an L3 transaction with zero reuse.)
// hj + h + weights live in LDS. Normal launch; 1 block/CU co-residency.
// ===========================================================================
struct FParams {
    const float *J, *b, *mpW1, *mpb1, *mpW2, *mpb2, *mpW3, *mpb3;
    const float *Wih, *Whh, *bih, *bhh;
    const float *rW1, *rb1, *rW2, *rb2, *rW3, *rb3;
    unsigned *hbg;        // 5 buffers, HB_STRIDE dwords apart
    unsigned *bar;        // barrier region (zeroed per launch)
    float *out;
};

__global__ __launch_bounds__(512, 1) void fused5_kernel(FParams p)
{
    extern __shared__ __align__(16) char smem[];
    const int tid  = threadIdx.x;
    const int bid  = blockIdx.x;
    const int lane = tid & 63;
    const int wave = tid >> 6;
    const int nsel = wave >> 2;
    const int nw   = wave & 3;
    const int j    = bid * 2 + nsel;
    const int q    = lane >> 4;
    const int c    = lane & 15;

    char* hbS = smem + OFF_HBS;
    float (*msum)[32]   = (float(*)[32])(smem + OFF_MSUM);
    float (*hPrevS)[32] = (float(*)[32])(smem + OFF_HPREV);
    float (*hS)[32]     = (float(*)[32])(smem + OFF_HS);
    float (*msgS)[32]   = (float(*)[32])(smem + OFF_MSG);
    float (*giS)[96]    = (float(*)[96])(smem + OFF_GI);
    float (*ghS)[96]    = (float(*)[96])(smem + OFF_GH);
    char*  hjL  = smem + OFF_HJ;
    float* w1tL = (float*)(smem + OFF_W1T);   // [d=0..66][cc], pitch 65
    float* wihL = (float*)(smem + OFF_WIH);   // [k=0..63][r], pitch 97
    float* whhL = (float*)(smem + OFF_WHH);   // [k=0..31][r], pitch 97
    char*  m2Lw = smem + OFF_M2L + wave * 2304;

    // ---- one-time: stage per-step weights into LDS ----
    for (int n = tid; n < 64 * 67; n += 512) {
        int cc = n / 67, d = n % 67;
        w1tL[d * 65 + cc] = p.mpW1[n];
    }
    for (int n = tid; n < 96 * 64; n += 512)
        wihL[(n & 63) * 97 + (n >> 6)] = p.Wih[n];
    for (int n = tid; n < 96 * 32; n += 512)
        whhL[(n & 31) * 97 + (n >> 5)] = p.Whh[n];

    // ---- invariant per-lane fragment gathers straight from inputs ----
    f16x8 Aw2[2][4], Aw3[2][2];
    #pragma unroll
    for (int f = 0; f < 2; ++f)
        #pragma unroll
        for (int t4 = 0; t4 < 4; ++t4) {
            const float* src = p.mpW2 + (t4 * 16 + c) * 64 + f * 32 + q * 8;
            floatx4 s0 = *(const floatx4*)(src);
            floatx4 s1 = *(const floatx4*)(src + 4);
            uintx4 u;
            u[0] = pkrtz(s0[0], s0[1]); u[1] = pkrtz(s0[2], s0[3]);
            u[2] = pkrtz(s1[0], s1[1]); u[3] = pkrtz(s1[2], s1[3]);
            Aw2[f][t4] = __builtin_bit_cast(f16x8, u);
        }
    #pragma unroll
    for (int f = 0; f < 2; ++f)
        #pragma unroll
        for (int t2 = 0; t2 < 2; ++t2) {
            const float* src = p.mpW3 + (t2 * 16 + c) * 64 + f * 32 + q * 8;
            floatx4 s0 = *(const floatx4*)(src);
            floatx4 s1 = *(const floatx4*)(src + 4);
            uintx4 u;
            u[0] = pkrtz(s0[0], s0[1]); u[1] = pkrtz(s0[2], s0[3]);
            u[2] = pkrtz(s1[0], s1[1]); u[3] = pkrtz(s1[2], s1[3]);
            Aw3[f][t2] = __builtin_bit_cast(f16x8, u);
        }
    uintx4 wja, wjb;
    #pragma unroll
    for (int i = 0; i < 4; ++i) {
        int r0 = q * 8 + 2 * i;
        wja[i] = pkrtz(p.mpW1[r0 * 67 + 64], p.mpW1[(r0 + 1) * 67 + 64]);
        int r1 = r0 + 32;
        wjb[i] = pkrtz(p.mpW1[r1 * 67 + 64], p.mpW1[(r1 + 1) * 67 + 64]);
    }
    floatx4 b2i[4], b3i[2];
    #pragma unroll
    for (int t4 = 0; t4 < 4; ++t4)
        #pragma unroll
        for (int r = 0; r < 4; ++r) b2i[t4][r] = p.mpb2[t4 * 16 + q * 4 + r];
    #pragma unroll
    for (int t2 = 0; t2 < 2; ++t2)
        #pragma unroll
        for (int r = 0; r < 4; ++r) b3i[t2][r] = p.mpb3[t2 * 16 + q * 4 + r];

    // J column j: one-time strided gather
    const float jA = p.J[((8 * q + nw) * 16 + c) * NN + j];
    const float jB = p.J[((8 * q + 4 + nw) * 16 + c) * NN + j];

    __syncthreads();   // w1tL ready

    // ---- initial projection (h = 0): hb[0] for own 2 nodes + hj -> LDS ----
    if (tid < 128) {
        int node = tid >> 6, cc = tid & 63;
        int jj = bid * 2 + node;
        float bj = p.b[jj];
        float si = bj * w1tL[65 * 65 + cc];
        float sj = bj * w1tL[66 * 65 + cc] + p.mpb1[cc];
        float sip = __shfl(si, lane ^ 1);
        float sjp = __shfl(sj, lane ^ 1);
        if (!(cc & 1)) {
            __hip_atomic_store(&p.hbg[jj * 32 + (cc >> 1)], pkrtz(si, sip),
                               __ATOMIC_RELAXED, __HIP_MEMORY_SCOPE_AGENT);
            *(unsigned*)(hjL + node * 128 + (cc >> 1) * 4) = pkrtz(sj, sjp);
        }
    }
    grid_bar(p.bar, 0);

    // ---------------- 5 fused steps ----------------
    #pragma unroll 1
    for (int t = 0; t < 5; ++t) {
        // ---- stage hb[t] (64 KB) -> LDS via normal CACHED loads ----
        {
            const uintx4* gp = (const uintx4*)(p.hbg + t * HB_STRIDE);
            uintx4 cr[8];
            #pragma unroll
            for (int k = 0; k < 8; ++k) cr[k] = gp[k * 512 + tid];
            #pragma unroll
            for (int k = 0; k < 8; ++k) {
                int row = k * 64 + (tid >> 3);
                *(uintx4*)(hbS + row * 144 + (tid & 7) * 16) = cr[k];
            }
        }
        uintx4 hja = *(const uintx4*)(hjL + nsel * 128 + q * 16);
        uintx4 hjb = *(const uintx4*)(hjL + nsel * 128 + 64 + q * 16);
        __syncthreads();

        float accf[2][4];
        #pragma unroll
        for (int t2 = 0; t2 < 2; ++t2)
            #pragma unroll
            for (int r = 0; r < 4; ++r) accf[t2][r] = 0.0f;

        auto edge_group = [&](int G, float Jv) {
            const char* rb = hbS + (G * 16 + c) * 144;
            uintx4 vlo = *(const uintx4*)(rb + q * 16);
            uintx4 vhi = *(const uintx4*)(rb + 64 + q * 16);
            const unsigned Jp = pkrtz(Jv, Jv);

            uintx4 a0u, a1u;
            #pragma unroll
            for (int i = 0; i < 4; ++i) {
                a0u[i] = pk_relu(pk_fma(Jp, wja[i], pk_add(vlo[i], hja[i])));
                a1u[i] = pk_relu(pk_fma(Jp, wjb[i], pk_add(vhi[i], hjb[i])));
            }
            f16x8 B0 = __builtin_bit_cast(f16x8, a0u);
            f16x8 B1 = __builtin_bit_cast(f16x8, a1u);

            floatx4 c1[4];
            #pragma unroll
            for (int t4 = 0; t4 < 4; ++t4) {
                c1[t4] = __builtin_amdgcn_mfma_f32_16x16x32_f16(Aw2[0][t4], B0, b2i[t4], 0, 0, 0);
                c1[t4] = __builtin_amdgcn_mfma_f32_16x16x32_f16(Aw2[1][t4], B1, c1[t4], 0, 0, 0);
            }
            #pragma unroll
            for (int t4 = 0; t4 < 4; ++t4) {
                unsigned p0 = pkrtz(fmaxf(c1[t4][0], 0.f), fmaxf(c1[t4][1], 0.f));
                unsigned p1 = pkrtz(fmaxf(c1[t4][2], 0.f), fmaxf(c1[t4][3], 0.f));
                *(uint2*)(m2Lw + c * 144 + t4 * 32 + q * 8) = make_uint2(p0, p1);
            }
            uintx4 rlo = *(const uintx4*)(m2Lw + c * 144 + q * 16);
            uintx4 rhi = *(const uintx4*)(m2Lw + c * 144 + 64 + q * 16);
            f16x8 B2lo = __builtin_bit_cast(f16x8, rlo);
            f16x8 B2hi = __builtin_bit_cast(f16x8, rhi);

            floatx4 c2[2];
            #pragma unroll
            for (int t2 = 0; t2 < 2; ++t2) {
                c2[t2] = __builtin_amdgcn_mfma_f32_16x16x32_f16(Aw3[0][t2], B2lo, b3i[t2], 0, 0, 0);
                c2[t2] = __builtin_amdgcn_mfma_f32_16x16x32_f16(Aw3[1][t2], B2hi, c2[t2], 0, 0, 0);
            }
            #pragma unroll
            for (int t2 = 0; t2 < 2; ++t2)
                #pragma unroll
                for (int r = 0; r < 4; ++r)
                    accf[t2][r] += fmaxf(c2[t2][r], 0.0f);
        };

        #pragma unroll
        for (int k = 0; k < 4; ++k) {
            edge_group(8 * k + nw,     __shfl(jA, k * 16 + c));
            edge_group(8 * k + 4 + nw, __shfl(jB, k * 16 + c));
        }

        #pragma unroll
        for (int m = 1; m < 16; m <<= 1)
            #pragma unroll
            for (int t2 = 0; t2 < 2; ++t2)
                #pragma unroll
                for (int r = 0; r < 4; ++r)
                    accf[t2][r] += __shfl_xor(accf[t2][r], m);
        if (c == 0) {
            #pragma unroll
            for (int t2 = 0; t2 < 2; ++t2)
                #pragma unroll
                for (int r = 0; r < 4; ++r)
                    msum[wave][t2 * 16 + q * 4 + r] = accf[t2][r];
        }
        __syncthreads();

        if (tid < 64) {
            int node = tid >> 5, d = tid & 31;
            msgS[node][d] = msum[node * 4 + 0][d] + msum[node * 4 + 1][d] +
                            msum[node * 4 + 2][d] + msum[node * 4 + 3][d];
        }
        __syncthreads();

        if (tid < 192) {
            int node = tid / 96, r = tid % 96;
            float a  = p.bih[r];
            float bb = p.bhh[r];
            if (t != 0) {
                #pragma unroll
                for (int k = 0; k < 32; ++k) {
                    float hv = hPrevS[node][k];
                    a  = fmaf(hv, wihL[k * 97 + r], a);
                    bb = fmaf(hv, whhL[k * 97 + r], bb);
                }
            }
            #pragma unroll
            for (int k = 0; k < 32; ++k)
                a = fmaf(msgS[node][k], wihL[(32 + k) * 97 + r], a);
            giS[node][r] = a; ghS[node][r] = bb;
        }
        __syncthreads();

        if (tid < 64) {
            int node = tid >> 5, d = tid & 31;
            float r  = sigmoidf_(giS[node][d] + ghS[node][d]);
            float z  = sigmoidf_(giS[node][32 + d] + ghS[node][32 + d]);
            float ng = tanhf(giS[node][64 + d] + r * ghS[node][64 + d]);
            float hold = (t == 0) ? 0.0f : hPrevS[node][d];
            float hv = (1.0f - z) * ng + z * hold;
            hS[node][d] = hv;
            hPrevS[node][d] = hv;
        }
        __syncthreads();

        if (t < 4) {
            if (tid < 128) {
                int node = tid >> 6, cc = tid & 63;
                int jj = bid * 2 + node;
                float bj = p.b[jj];
                float si = bj * w1tL[65 * 65 + cc];
                float sj = bj * w1tL[66 * 65 + cc] + p.mpb1[cc];
                #pragma unroll
                for (int d = 0; d < 32; ++d) {
                    float hv = hS[node][d];
                    si = fmaf(hv, w1tL[d * 65 + cc], si);
                    sj = fmaf(hv, w1tL[(32 + d) * 65 + cc], sj);
                }
                float sip = __shfl(si, lane ^ 1);
                float sjp = __shfl(sj, lane ^ 1);
                if (!(cc & 1)) {
                    __hip_atomic_store(&p.hbg[(t + 1) * HB_STRIDE + jj * 32 + (cc >> 1)],
                                       pkrtz(si, sip),
                                       __ATOMIC_RELAXED, __HIP_MEMORY_SCOPE_AGENT);
                    *(unsigned*)(hjL + node * 128 + (cc >> 1) * 4) = pkrtz(sj, sjp);
                }
            }
            grid_bar(p.bar, t + 1);
        } else {
            if (wave < 2) {
                int node = wave;
                int jj = bid * 2 + node;
                float y1 = p.rb1[lane];
                const floatx4* w1p = (const floatx4*)(p.rW1 + lane * 32);
                #pragma unroll
                for (int kk = 0; kk < 8; ++kk) {
                    floatx4 v = w1p[kk];
                    #pragma unroll
                    for (int i = 0; i < 4; ++i)
                        y1 = fmaf(hS[node][kk * 4 + i], v[i], y1);
                }
                y1 = fmaxf(y1, 0.0f);
                float y2 = p.rb2[lane];
                const floatx4* w2p = (const floatx4*)(p.rW2 + lane * 64);
                #pragma unroll
                for (int kk = 0; kk < 16; ++kk) {
                    floatx4 v = w2p[kk];
                    #pragma unroll
                    for (int i = 0; i < 4; ++i)
                        y2 = fmaf(__shfl(y1, kk * 4 + i), v[i], y2);
                }
                y2 = fmaxf(y2, 0.0f);
                float y3 = (lane < 2) ? p.rb3[lane] : 0.0f;
                #pragma unroll
                for (int k = 0; k < 64; ++k) {
                    float v = __shfl(y2, k);
                    if (lane < 2) y3 = fmaf(v, p.rW3[lane * 64 + k], y3);
                }
                if (lane < 2) p.out[jj * 2 + lane] = sigmoidf_(y3);
            }
        }
    }
}

// ---------------------------------------------------------------------------
extern "C" void kernel_launch(void* const* d_in, const int* in_sizes, int n_in,
                              void* d_out, int out_size, void* d_ws, size_t ws_size,
                              hipStream_t stream)
{
    float* ws = (float*)d_ws;

    const float* J    = (const float*)d_in[0];
    const float* b    = (const float*)d_in[1];
    const float* mpW1 = (const float*)d_in[2];
    const float* mpb1 = (const float*)d_in[3];
    const float* mpW2 = (const float*)d_in[4];
    const float* mpb2 = (const float*)d_in[5];
    const float* mpW3 = (const float*)d_in[6];
    const float* mpb3 = (const float*)d_in[7];
    const float* Wih  = (const float*)d_in[8];
    const float* Whh  = (const float*)d_in[9];
    const float* bih  = (const float*)d_in[10];
    const float* bhh  = (const float*)d_in[11];
    const float* rW1  = (const float*)d_in[12];
    const float* rb1  = (const float*)d_in[13];
    const float* rW2  = (const float*)d_in[14];
    const float* rb2  = (const float*)d_in[15];
    const float* rW3  = (const float*)d_in[16];
    const float* rb3  = (const float*)d_in[17];

    // hb chain (5 buffers, 128 KB apart) + barrier region, 8 MB into workspace
    unsigned* hbg = (unsigned*)(ws + 2097152);                 // 5*HB_STRIDE dwords
    unsigned* bar = (unsigned*)(ws + 2097152 + 5 * HB_STRIDE); // 32 KB region

    (void)hipFuncSetAttribute((const void*)fused5_kernel,
                              hipFuncAttributeMaxDynamicSharedMemorySize, LDS_TOTAL);

    FParams fp;
    fp.J = J; fp.b = b; fp.mpW1 = mpW1; fp.mpb1 = mpb1; fp.mpW2 = mpW2;
    fp.mpb2 = mpb2; fp.mpW3 = mpW3; fp.mpb3 = mpb3;
    fp.Wih = Wih; fp.Whh = Whh; fp.bih = bih; fp.bhh = bhh;
    fp.rW1 = rW1; fp.rb1 = rb1; fp.rW2 = rW2; fp.rb2 = rb2; fp.rW3 = rW3; fp.rb3 = rb3;
    fp.hbg = hbg; fp.bar = bar;
    fp.out = (float*)d_out;

    // zero the barrier region every run (workspace is re-poisoned)
    (void)hipMemsetAsync((void*)bar, 0, 32768, stream);

    fused5_kernel<<<dim3(NB), dim3(512), LDS_TOTAL, stream>>>(fp);
}

// Round 7
// 236.565 us; speedup vs baseline: 1.3798x; 1.3798x over previous
//
#include <hip/hip_runtime.h>
#include <math.h>

#define NN 512
#define SD 32
#define HM 64
#define NB 256   // grid blocks = CU count; 1 block/CU (LDS-limited) => co-resident (proven R4/R5)

typedef _Float16 f16x8 __attribute__((ext_vector_type(8)));
typedef float floatx4 __attribute__((ext_vector_type(4)));
typedef unsigned uintx4 __attribute__((ext_vector_type(4)));

// ---- dynamic LDS layout (bytes) ----
#define OFF_HBS   0        // 512 rows x 144 B packed-f16 hip        = 73728
#define OFF_M2L   73728    // 8 waves x 2304 B                       = 18432
#define OFF_MSUM  92160    // 8x32 f32
#define OFF_HPREV 93184    // 2x32 f32
#define OFF_HS    93440    // 2x32 f32
#define OFF_MSG   93696    // 2x32 f32
#define OFF_GI    93952    // 2x96 f32
#define OFF_GH    94720    // 2x96 f32
#define OFF_HJ    95488    // 2 nodes x 128 B packed-f16 hj          = 256
#define OFF_W1T   95744    // 67x65 f32 (pad 65)                     = 17420
#define OFF_WIH   113168   // 64x97 f32 ([k][r], pad 97)             = 24832
#define OFF_WHH   138000   // 32x97 f32 ([k][r], pad 97)             = 12416
#define LDS_TOTAL 150416   // < 160 KiB/CU

#define HB_STRIDE 32768    // hb buffers 128 KB apart

__device__ __forceinline__ float sigmoidf_(float x) {
    return 1.0f / (1.0f + __expf(-x));
}
__device__ __forceinline__ unsigned pkrtz(float a, float b) {
    unsigned r;
    asm("v_cvt_pkrtz_f16_f32 %0, %1, %2" : "=v"(r) : "v"(a), "v"(b));
    return r;
}
__device__ __forceinline__ unsigned pk_add(unsigned a, unsigned b) {
    unsigned r;
    asm("v_pk_add_f16 %0, %1, %2" : "=v"(r) : "v"(a), "v"(b));
    return r;
}
__device__ __forceinline__ unsigned pk_fma(unsigned a, unsigned b, unsigned c) {
    unsigned r;
    asm("v_pk_fma_f16 %0, %1, %2, %3" : "=v"(r) : "v"(a), "v"(b), "v"(c));
    return r;
}
__device__ __forceinline__ unsigned pk_relu(unsigned a) {
    unsigned r, z = 0u;
    asm("v_pk_max_f16 %0, %1, %2" : "=v"(r) : "v"(a), "v"(z));
    return r;
}
// 16B L2-bypassing load (L3 point read) — R4-verified staging path.
__device__ __forceinline__ uintx4 load_b128_sc1(const uintx4* p) {
    uintx4 r;
    asm volatile("global_load_dwordx4 %0, %1, off sc1" : "=v"(r) : "v"(p));
    return r;
}

// ---------------------------------------------------------------------------
// Grid barrier v3: arrival = 2-level tree on separate 128 B lines (as R5,
// verified); release = FANNED OUT to 8 per-group rdy words (128 B apart) so
// each line is polled by only 32 blocks instead of 256 (R5's single rdy
// line was polled by 256 CUs every ~0.4 us -> L3 bank saturation inflating
// release latency). RELAXED sc1 point-ops only; no agent acquire/release
// fences (R2: those writeback/invalidate whole L2s). __syncthreads() before
// arrival drains vmcnt so this block's sc1 stores are at L3 before its
// count bumps. Protocol otherwise identical to R3/R4/R5 (absmax 0.0 x3).
// ---------------------------------------------------------------------------
__device__ __forceinline__ void grid_bar(unsigned* bar, int bi)
{
    __syncthreads();
    if (threadIdx.x == 0) {
        const int grp = (int)blockIdx.x >> 5;
        unsigned* cg = bar + (bi * 16 + grp) * 32;
        unsigned old = __hip_atomic_fetch_add(cg, 1u, __ATOMIC_RELAXED,
                                              __HIP_MEMORY_SCOPE_AGENT);
        if (old == 31u) {
            unsigned* cr = bar + (bi * 16 + 8) * 32;
            unsigned o2 = __hip_atomic_fetch_add(cr, 1u, __ATOMIC_RELAXED,
                                                 __HIP_MEMORY_SCOPE_AGENT);
            if (o2 == 7u) {
                #pragma unroll
                for (int g = 0; g < 8; ++g)
                    __hip_atomic_store(bar + 4096 + g * 32, (unsigned)(bi + 1),
                                       __ATOMIC_RELAXED, __HIP_MEMORY_SCOPE_AGENT);
            }
        }
        while (__hip_atomic_load(bar + 4096 + grp * 32, __ATOMIC_RELAXED,
                                 __HIP_MEMORY_SCOPE_AGENT) < (unsigned)(bi + 1))
            __builtin_amdgcn_s_sleep(32);
        (void)__hip_atomic_load(bar + 4096 + grp * 32, __ATOMIC_ACQUIRE,
                                __HIP_MEMORY_SCOPE_AGENT);
    }
    __syncthreads();
}

// ===========================================================================
// Persistent fused kernel v6. Protocol = R4/R5 (sc1 write-through stores,
// asm 16B sc1 L3 staging reads). Changes vs R5: (1) edge loop NOT unrolled
// (one edge_group instantiation -> step body fits I$; the unrolled body was
// streamed by all 8 lockstep waves every step with nothing to hide I$ miss
// stalls); (2) barrier release fan-out. Everything else identical.
// ===========================================================================
struct FParams {
    const float *J, *b, *mpW1, *mpb1, *mpW2, *mpb2, *mpW3, *mpb3;
    const float *Wih, *Whh, *bih, *bhh;
    const float *rW1, *rb1, *rW2, *rb2, *rW3, *rb3;
    unsigned *hbg;        // 5 buffers, HB_STRIDE dwords apart
    unsigned *bar;        // barrier region (zeroed per launch)
    float *out;
};

__global__ __launch_bounds__(512, 1) void fused6_kernel(FParams p)
{
    extern __shared__ __align__(16) char smem[];
    const int tid  = threadIdx.x;
    const int bid  = blockIdx.x;
    const int lane = tid & 63;
    const int wave = tid >> 6;
    const int nsel = wave >> 2;
    const int nw   = wave & 3;
    const int j    = bid * 2 + nsel;
    const int q    = lane >> 4;
    const int c    = lane & 15;

    char* hbS = smem + OFF_HBS;
    float (*msum)[32]   = (float(*)[32])(smem + OFF_MSUM);
    float (*hPrevS)[32] = (float(*)[32])(smem + OFF_HPREV);
    float (*hS)[32]     = (float(*)[32])(smem + OFF_HS);
    float (*msgS)[32]   = (float(*)[32])(smem + OFF_MSG);
    float (*giS)[96]    = (float(*)[96])(smem + OFF_GI);
    float (*ghS)[96]    = (float(*)[96])(smem + OFF_GH);
    char*  hjL  = smem + OFF_HJ;
    float* w1tL = (float*)(smem + OFF_W1T);   // [d=0..66][cc], pitch 65
    float* wihL = (float*)(smem + OFF_WIH);   // [k=0..63][r], pitch 97
    float* whhL = (float*)(smem + OFF_WHH);   // [k=0..31][r], pitch 97
    char*  m2Lw = smem + OFF_M2L + wave * 2304;

    // ---- one-time: stage per-step weights into LDS ----
    for (int n = tid; n < 64 * 67; n += 512) {
        int cc = n / 67, d = n % 67;
        w1tL[d * 65 + cc] = p.mpW1[n];
    }
    for (int n = tid; n < 96 * 64; n += 512)
        wihL[(n & 63) * 97 + (n >> 6)] = p.Wih[n];
    for (int n = tid; n < 96 * 32; n += 512)
        whhL[(n & 31) * 97 + (n >> 5)] = p.Whh[n];

    // ---- invariant per-lane fragment gathers straight from inputs ----
    f16x8 Aw2[2][4], Aw3[2][2];
    #pragma unroll
    for (int f = 0; f < 2; ++f)
        #pragma unroll
        for (int t4 = 0; t4 < 4; ++t4) {
            const float* src = p.mpW2 + (t4 * 16 + c) * 64 + f * 32 + q * 8;
            floatx4 s0 = *(const floatx4*)(src);
            floatx4 s1 = *(const floatx4*)(src + 4);
            uintx4 u;
            u[0] = pkrtz(s0[0], s0[1]); u[1] = pkrtz(s0[2], s0[3]);
            u[2] = pkrtz(s1[0], s1[1]); u[3] = pkrtz(s1[2], s1[3]);
            Aw2[f][t4] = __builtin_bit_cast(f16x8, u);
        }
    #pragma unroll
    for (int f = 0; f < 2; ++f)
        #pragma unroll
        for (int t2 = 0; t2 < 2; ++t2) {
            const float* src = p.mpW3 + (t2 * 16 + c) * 64 + f * 32 + q * 8;
            floatx4 s0 = *(const floatx4*)(src);
            floatx4 s1 = *(const floatx4*)(src + 4);
            uintx4 u;
            u[0] = pkrtz(s0[0], s0[1]); u[1] = pkrtz(s0[2], s0[3]);
            u[2] = pkrtz(s1[0], s1[1]); u[3] = pkrtz(s1[2], s1[3]);
            Aw3[f][t2] = __builtin_bit_cast(f16x8, u);
        }
    uintx4 wja, wjb;
    #pragma unroll
    for (int i = 0; i < 4; ++i) {
        int r0 = q * 8 + 2 * i;
        wja[i] = pkrtz(p.mpW1[r0 * 67 + 64], p.mpW1[(r0 + 1) * 67 + 64]);
        int r1 = r0 + 32;
        wjb[i] = pkrtz(p.mpW1[r1 * 67 + 64], p.mpW1[(r1 + 1) * 67 + 64]);
    }
    floatx4 b2i[4], b3i[2];
    #pragma unroll
    for (int t4 = 0; t4 < 4; ++t4)
        #pragma unroll
        for (int r = 0; r < 4; ++r) b2i[t4][r] = p.mpb2[t4 * 16 + q * 4 + r];
    #pragma unroll
    for (int t2 = 0; t2 < 2; ++t2)
        #pragma unroll
        for (int r = 0; r < 4; ++r) b3i[t2][r] = p.mpb3[t2 * 16 + q * 4 + r];

    // J column j: one-time strided gather
    const float jA = p.J[((8 * q + nw) * 16 + c) * NN + j];
    const float jB = p.J[((8 * q + 4 + nw) * 16 + c) * NN + j];

    __syncthreads();   // w1tL ready

    // ---- initial projection (h = 0): hb[0] for own 2 nodes + hj -> LDS ----
    if (tid < 128) {
        int node = tid >> 6, cc = tid & 63;
        int jj = bid * 2 + node;
        float bj = p.b[jj];
        float si = bj * w1tL[65 * 65 + cc];
        float sj = bj * w1tL[66 * 65 + cc] + p.mpb1[cc];
        float sip = __shfl(si, lane ^ 1);
        float sjp = __shfl(sj, lane ^ 1);
        if (!(cc & 1)) {
            __hip_atomic_store(&p.hbg[jj * 32 + (cc >> 1)], pkrtz(si, sip),
                               __ATOMIC_RELAXED, __HIP_MEMORY_SCOPE_AGENT);
            *(unsigned*)(hjL + node * 128 + (cc >> 1) * 4) = pkrtz(sj, sjp);
        }
    }
    grid_bar(p.bar, 0);

    // ---------------- 5 fused steps ----------------
    #pragma unroll 1
    for (int t = 0; t < 5; ++t) {
        // ---- stage hb[t] (64 KB) -> LDS via asm 16B sc1 L3 reads (R4 path) ----
        {
            const uintx4* gp = (const uintx4*)(p.hbg + t * HB_STRIDE);
            uintx4 cr[8];
            #pragma unroll
            for (int k = 0; k < 8; ++k)
                cr[k] = load_b128_sc1(gp + k * 512 + tid);
            asm volatile("s_waitcnt vmcnt(0)" ::: "memory");
            __builtin_amdgcn_sched_barrier(0);
            #pragma unroll
            for (int k = 0; k < 8; ++k) {
                int row = k * 64 + (tid >> 3);
                *(uintx4*)(hbS + row * 144 + (tid & 7) * 16) = cr[k];
            }
        }
        uintx4 hja = *(const uintx4*)(hjL + nsel * 128 + q * 16);
        uintx4 hjb = *(const uintx4*)(hjL + nsel * 128 + 64 + q * 16);
        __syncthreads();

        float accf[2][4];
        #pragma unroll
        for (int t2 = 0; t2 < 2; ++t2)
            #pragma unroll
            for (int r = 0; r < 4; ++r) accf[t2][r] = 0.0f;

        // ---- 8 edge groups: NOT unrolled (code-size / I$ — the R5 body
        //      was ~8x this and streamed by lockstep waves every step) ----
        #pragma unroll 1
        for (int kk = 0; kk < 8; ++kk) {
            const int k4  = kk >> 1;
            const int G   = 8 * k4 + ((kk & 1) ? 4 : 0) + nw;
            const float Jv = __shfl((kk & 1) ? jB : jA, k4 * 16 + c);

            const char* rb = hbS + (G * 16 + c) * 144;
            uintx4 vlo = *(const uintx4*)(rb + q * 16);
            uintx4 vhi = *(const uintx4*)(rb + 64 + q * 16);
            const unsigned Jp = pkrtz(Jv, Jv);

            uintx4 a0u, a1u;
            #pragma unroll
            for (int i = 0; i < 4; ++i) {
                a0u[i] = pk_relu(pk_fma(Jp, wja[i], pk_add(vlo[i], hja[i])));
                a1u[i] = pk_relu(pk_fma(Jp, wjb[i], pk_add(vhi[i], hjb[i])));
            }
            f16x8 B0 = __builtin_bit_cast(f16x8, a0u);
            f16x8 B1 = __builtin_bit_cast(f16x8, a1u);

            floatx4 c1[4];
            #pragma unroll
            for (int t4 = 0; t4 < 4; ++t4) {
                c1[t4] = __builtin_amdgcn_mfma_f32_16x16x32_f16(Aw2[0][t4], B0, b2i[t4], 0, 0, 0);
                c1[t4] = __builtin_amdgcn_mfma_f32_16x16x32_f16(Aw2[1][t4], B1, c1[t4], 0, 0, 0);
            }
            #pragma unroll
            for (int t4 = 0; t4 < 4; ++t4) {
                unsigned p0 = pkrtz(fmaxf(c1[t4][0], 0.f), fmaxf(c1[t4][1], 0.f));
                unsigned p1 = pkrtz(fmaxf(c1[t4][2], 0.f), fmaxf(c1[t4][3], 0.f));
                *(uint2*)(m2Lw + c * 144 + t4 * 32 + q * 8) = make_uint2(p0, p1);
            }
            uintx4 rlo = *(const uintx4*)(m2Lw + c * 144 + q * 16);
            uintx4 rhi = *(const uintx4*)(m2Lw + c * 144 + 64 + q * 16);
            f16x8 B2lo = __builtin_bit_cast(f16x8, rlo);
            f16x8 B2hi = __builtin_bit_cast(f16x8, rhi);

            floatx4 c2[2];
            #pragma unroll
            for (int t2 = 0; t2 < 2; ++t2) {
                c2[t2] = __builtin_amdgcn_mfma_f32_16x16x32_f16(Aw3[0][t2], B2lo, b3i[t2], 0, 0, 0);
                c2[t2] = __builtin_amdgcn_mfma_f32_16x16x32_f16(Aw3[1][t2], B2hi, c2[t2], 0, 0, 0);
            }
            #pragma unroll
            for (int t2 = 0; t2 < 2; ++t2)
                #pragma unroll
                for (int r = 0; r < 4; ++r)
                    accf[t2][r] += fmaxf(c2[t2][r], 0.0f);
        }

        #pragma unroll
        for (int m = 1; m < 16; m <<= 1)
            #pragma unroll
            for (int t2 = 0; t2 < 2; ++t2)
                #pragma unroll
                for (int r = 0; r < 4; ++r)
                    accf[t2][r] += __shfl_xor(accf[t2][r], m);
        if (c == 0) {
            #pragma unroll
            for (int t2 = 0; t2 < 2; ++t2)
                #pragma unroll
                for (int r = 0; r < 4; ++r)
                    msum[wave][t2 * 16 + q * 4 + r] = accf[t2][r];
        }
        __syncthreads();

        if (tid < 64) {
            int node = tid >> 5, d = tid & 31;
            msgS[node][d] = msum[node * 4 + 0][d] + msum[node * 4 + 1][d] +
                            msum[node * 4 + 2][d] + msum[node * 4 + 3][d];
        }
        __syncthreads();

        if (tid < 192) {
            int node = tid / 96, r = tid % 96;
            float a  = p.bih[r];
            float bb = p.bhh[r];
            if (t != 0) {
                #pragma unroll
                for (int k = 0; k < 32; ++k) {
                    float hv = hPrevS[node][k];
                    a  = fmaf(hv, wihL[k * 97 + r], a);
                    bb = fmaf(hv, whhL[k * 97 + r], bb);
                }
            }
            #pragma unroll
            for (int k = 0; k < 32; ++k)
                a = fmaf(msgS[node][k], wihL[(32 + k) * 97 + r], a);
            giS[node][r] = a; ghS[node][r] = bb;
        }
        __syncthreads();

        if (tid < 64) {
            int node = tid >> 5, d = tid & 31;
            float r  = sigmoidf_(giS[node][d] + ghS[node][d]);
            float z  = sigmoidf_(giS[node][32 + d] + ghS[node][32 + d]);
            float ng = tanhf(giS[node][64 + d] + r * ghS[node][64 + d]);
            float hold = (t == 0) ? 0.0f : hPrevS[node][d];
            float hv = (1.0f - z) * ng + z * hold;
            hS[node][d] = hv;
            hPrevS[node][d] = hv;
        }
        __syncthreads();

        if (t < 4) {
            if (tid < 128) {
                int node = tid >> 6, cc = tid & 63;
                int jj = bid * 2 + node;
                float bj = p.b[jj];
                float si = bj * w1tL[65 * 65 + cc];
                float sj = bj * w1tL[66 * 65 + cc] + p.mpb1[cc];
                #pragma unroll
                for (int d = 0; d < 32; ++d) {
                    float hv = hS[node][d];
                    si = fmaf(hv, w1tL[d * 65 + cc], si);
                    sj = fmaf(hv, w1tL[(32 + d) * 65 + cc], sj);
                }
                float sip = __shfl(si, lane ^ 1);
                float sjp = __shfl(sj, lane ^ 1);
                if (!(cc & 1)) {
                    __hip_atomic_store(&p.hbg[(t + 1) * HB_STRIDE + jj * 32 + (cc >> 1)],
                                       pkrtz(si, sip),
                                       __ATOMIC_RELAXED, __HIP_MEMORY_SCOPE_AGENT);
                    *(unsigned*)(hjL + node * 128 + (cc >> 1) * 4) = pkrtz(sj, sjp);
                }
            }
            grid_bar(p.bar, t + 1);
        } else {
            if (wave < 2) {
                int node = wave;
                int jj = bid * 2 + node;
                float y1 = p.rb1[lane];
                const floatx4* w1p = (const floatx4*)(p.rW1 + lane * 32);
                #pragma unroll
                for (int kk = 0; kk < 8; ++kk) {
                    floatx4 v = w1p[kk];
                    #pragma unroll
                    for (int i = 0; i < 4; ++i)
                        y1 = fmaf(hS[node][kk * 4 + i], v[i], y1);
                }
                y1 = fmaxf(y1, 0.0f);
                float y2 = p.rb2[lane];
                const floatx4* w2p = (const floatx4*)(p.rW2 + lane * 64);
                #pragma unroll
                for (int kk = 0; kk < 16; ++kk) {
                    floatx4 v = w2p[kk];
                    #pragma unroll
                    for (int i = 0; i < 4; ++i)
                        y2 = fmaf(__shfl(y1, kk * 4 + i), v[i], y2);
                }
                y2 = fmaxf(y2, 0.0f);
                float y3 = (lane < 2) ? p.rb3[lane] : 0.0f;
                #pragma unroll
                for (int k = 0; k < 64; ++k) {
                    float v = __shfl(y2, k);
                    if (lane < 2) y3 = fmaf(v, p.rW3[lane * 64 + k], y3);
                }
                if (lane < 2) p.out[jj * 2 + lane] = sigmoidf_(y3);
            }
        }
    }
}

// ---------------------------------------------------------------------------
extern "C" void kernel_launch(void* const* d_in, const int* in_sizes, int n_in,
                              void* d_out, int out_size, void* d_ws, size_t ws_size,
                              hipStream_t stream)
{
    float* ws = (float*)d_ws;

    const float* J    = (const float*)d_in[0];
    const float* b    = (const float*)d_in[1];
    const float* mpW1 = (const float*)d_in[2];
    const float* mpb1 = (const float*)d_in[3];
    const float* mpW2 = (const float*)d_in[4];
    const float* mpb2 = (const float*)d_in[5];
    const float* mpW3 = (const float*)d_in[6];
    const float* mpb3 = (const float*)d_in[7];
    const float* Wih  = (const float*)d_in[8];
    const float* Whh  = (const float*)d_in[9];
    const float* bih  = (const float*)d_in[10];
    const float* bhh  = (const float*)d_in[11];
    const float* rW1  = (const float*)d_in[12];
    const float* rb1  = (const float*)d_in[13];
    const float* rW2  = (const float*)d_in[14];
    const float* rb2  = (const float*)d_in[15];
    const float* rW3  = (const float*)d_in[16];
    const float* rb3  = (const float*)d_in[17];

    // hb chain (5 buffers, 128 KB apart) + barrier region, 8 MB into workspace
    unsigned* hbg = (unsigned*)(ws + 2097152);                 // 5*HB_STRIDE dwords
    unsigned* bar = (unsigned*)(ws + 2097152 + 5 * HB_STRIDE); // 32 KB region

    (void)hipFuncSetAttribute((const void*)fused6_kernel,
                              hipFuncAttributeMaxDynamicSharedMemorySize, LDS_TOTAL);

    FParams fp;
    fp.J = J; fp.b = b; fp.mpW1 = mpW1; fp.mpb1 = mpb1; fp.mpW2 = mpW2;
    fp.mpb2 = mpb2; fp.mpW3 = mpW3; fp.mpb3 = mpb3;
    fp.Wih = Wih; fp.Whh = Whh; fp.bih = bih; fp.bhh = bhh;
    fp.rW1 = rW1; fp.rb1 = rb1; fp.rW2 = rW2; fp.rb2 = rb2; fp.rW3 = rW3; fp.rb3 = rb3;
    fp.hbg = hbg; fp.bar = bar;
    fp.out = (float*)d_out;

    // zero the barrier region every run (workspace is re-poisoned)
    (void)hipMemsetAsync((void*)bar, 0, 32768, stream);

    fused6_kernel<<<dim3(NB), dim3(512), LDS_TOTAL, stream>>>(fp);
}

// Round 8
// 185.022 us; speedup vs baseline: 1.7641x; 1.2786x over previous
//
#include <hip/hip_runtime.h>
#include <math.h>

#define NN 512
#define SD 32
#define HM 64
#define NB 256

typedef _Float16 f16x8 __attribute__((ext_vector_type(8)));
typedef float floatx4 __attribute__((ext_vector_type(4)));
typedef unsigned uintx4 __attribute__((ext_vector_type(4)));

// ---- dynamic LDS layout (bytes) ----
#define OFF_HBS   0        // 512 rows x 144 B packed-f16 hip        = 73728
#define OFF_M2L   73728    // 8 waves x 2304 B                       = 18432
#define OFF_MSUM  92160    // 8x32 f32
#define OFF_HPREV 93184    // 2x32 f32
#define OFF_HS    93440    // 2x32 f32
#define OFF_MSG   93696    // 2x32 f32
#define OFF_GI    93952    // 2x96 f32
#define OFF_GH    94720    // 2x96 f32
#define OFF_HJ    95488    // 2 nodes x 128 B packed-f16 hj          = 256
#define OFF_W1T   95744    // 67x65 f32 (pad 65)                     = 17420
#define OFF_WIH   113168   // 64x97 f32 ([k][r], pad 97)             = 24832
#define OFF_WHH   138000   // 32x97 f32 ([k][r], pad 97)             = 12416
#define LDS_TOTAL 150416   // < 160 KiB/CU

__device__ __forceinline__ float sigmoidf_(float x) {
    return 1.0f / (1.0f + __expf(-x));
}
__device__ __forceinline__ unsigned pkrtz(float a, float b) {
    unsigned r;
    asm("v_cvt_pkrtz_f16_f32 %0, %1, %2" : "=v"(r) : "v"(a), "v"(b));
    return r;
}
__device__ __forceinline__ unsigned pk_add(unsigned a, unsigned b) {
    unsigned r;
    asm("v_pk_add_f16 %0, %1, %2" : "=v"(r) : "v"(a), "v"(b));
    return r;
}
__device__ __forceinline__ unsigned pk_fma(unsigned a, unsigned b, unsigned c) {
    unsigned r;
    asm("v_pk_fma_f16 %0, %1, %2, %3" : "=v"(r) : "v"(a), "v"(b), "v"(c));
    return r;
}
__device__ __forceinline__ unsigned pk_relu(unsigned a) {
    unsigned r, z = 0u;
    asm("v_pk_max_f16 %0, %1, %2" : "=v"(r) : "v"(a), "v"(z));
    return r;
}

// ===========================================================================
// Self-contained per-step kernel (no prep dispatch, no grid barrier).
// Cross-step exchange: plain cached global stores/loads; coherence comes
// from the dispatch boundary (runtime kernel-end writeback + kernel-begin
// invalidate) — the R1-verified protocol, which per-step costs ~2 us vs the
// ~20 us/step of the fused kernels' software barrier + sc1 L3 staging
// (R3-R7 post-mortems). Per-dispatch one-time work: weight staging into
// padded LDS + per-lane fragment packing + direct J gather (all verified
// in fused3..7). Dispatch 0 computes the h=0 projection in-LDS directly.
// ===========================================================================
struct SParams {
    const float *J, *b, *mpW1, *mpb1, *mpW2, *mpb2, *mpW3, *mpb3;
    const float *Wih, *Whh, *bih, *bhh;
    const float *rW1, *rb1, *rW2, *rb2, *rW3, *rb3;
    const unsigned *hbR; unsigned *hbW;   // packed hip exchange (ping-pong)
    const unsigned *hjR; unsigned *hjW;   // packed hj exchange (ping-pong)
    const float *hR;     float *hW;       // h state exchange (ping-pong)
    float *out;
    int hzero, rdout;
};

__global__ __launch_bounds__(512, 1) void step7_kernel(SParams s)
{
    extern __shared__ __align__(16) char smem[];
    const int tid  = threadIdx.x;
    const int bid  = blockIdx.x;
    const int lane = tid & 63;
    const int wave = tid >> 6;
    const int nsel = wave >> 2;
    const int nw   = wave & 3;
    const int j    = bid * 2 + nsel;
    const int q    = lane >> 4;
    const int c    = lane & 15;

    char* hbS = smem + OFF_HBS;
    float (*msum)[32]   = (float(*)[32])(smem + OFF_MSUM);
    float (*hPrevS)[32] = (float(*)[32])(smem + OFF_HPREV);
    float (*hS)[32]     = (float(*)[32])(smem + OFF_HS);
    float (*msgS)[32]   = (float(*)[32])(smem + OFF_MSG);
    float (*giS)[96]    = (float(*)[96])(smem + OFF_GI);
    float (*ghS)[96]    = (float(*)[96])(smem + OFF_GH);
    char*  hjL  = smem + OFF_HJ;
    float* w1tL = (float*)(smem + OFF_W1T);   // [d=0..66][cc], pitch 65
    float* wihL = (float*)(smem + OFF_WIH);   // [k=0..63][r], pitch 97
    float* whhL = (float*)(smem + OFF_WHH);   // [k=0..31][r], pitch 97
    char*  m2Lw = smem + OFF_M2L + wave * 2304;

    // ---- one-time (per dispatch): stage weights into padded LDS ----
    for (int n = tid; n < 64 * 67; n += 512) {
        int cc = n / 67, d = n % 67;
        w1tL[d * 65 + cc] = s.mpW1[n];
    }
    for (int n = tid; n < 96 * 64; n += 512)
        wihL[(n & 63) * 97 + (n >> 6)] = s.Wih[n];
    for (int n = tid; n < 96 * 32; n += 512)
        whhL[(n & 31) * 97 + (n >> 5)] = s.Whh[n];

    // ---- one-time: per-lane MFMA fragment packs from raw inputs ----
    f16x8 Aw2[2][4], Aw3[2][2];
    #pragma unroll
    for (int f = 0; f < 2; ++f)
        #pragma unroll
        for (int t4 = 0; t4 < 4; ++t4) {
            const float* src = s.mpW2 + (t4 * 16 + c) * 64 + f * 32 + q * 8;
            floatx4 s0 = *(const floatx4*)(src);
            floatx4 s1 = *(const floatx4*)(src + 4);
            uintx4 u;
            u[0] = pkrtz(s0[0], s0[1]); u[1] = pkrtz(s0[2], s0[3]);
            u[2] = pkrtz(s1[0], s1[1]); u[3] = pkrtz(s1[2], s1[3]);
            Aw2[f][t4] = __builtin_bit_cast(f16x8, u);
        }
    #pragma unroll
    for (int f = 0; f < 2; ++f)
        #pragma unroll
        for (int t2 = 0; t2 < 2; ++t2) {
            const float* src = s.mpW3 + (t2 * 16 + c) * 64 + f * 32 + q * 8;
            floatx4 s0 = *(const floatx4*)(src);
            floatx4 s1 = *(const floatx4*)(src + 4);
            uintx4 u;
            u[0] = pkrtz(s0[0], s0[1]); u[1] = pkrtz(s0[2], s0[3]);
            u[2] = pkrtz(s1[0], s1[1]); u[3] = pkrtz(s1[2], s1[3]);
            Aw3[f][t2] = __builtin_bit_cast(f16x8, u);
        }
    uintx4 wja, wjb;
    #pragma unroll
    for (int i = 0; i < 4; ++i) {
        int r0 = q * 8 + 2 * i;
        wja[i] = pkrtz(s.mpW1[r0 * 67 + 64], s.mpW1[(r0 + 1) * 67 + 64]);
        int r1 = r0 + 32;
        wjb[i] = pkrtz(s.mpW1[r1 * 67 + 64], s.mpW1[(r1 + 1) * 67 + 64]);
    }
    floatx4 b2i[4], b3i[2];
    #pragma unroll
    for (int t4 = 0; t4 < 4; ++t4)
        #pragma unroll
        for (int r = 0; r < 4; ++r) b2i[t4][r] = s.mpb2[t4 * 16 + q * 4 + r];
    #pragma unroll
    for (int t2 = 0; t2 < 2; ++t2)
        #pragma unroll
        for (int r = 0; r < 4; ++r) b3i[t2][r] = s.mpb3[t2 * 16 + q * 4 + r];

    // J column j: direct strided gather (L2-resident after dispatch 0)
    const float jA = s.J[((8 * q + nw) * 16 + c) * NN + j];
    const float jB = s.J[((8 * q + 4 + nw) * 16 + c) * NN + j];

    uintx4 hja, hjb;
    if (!s.hzero) {
        // ---- stage hb (64 KB) -> LDS via plain cached loads (R1 path) ----
        {
            uintx4 cr[8];
            const uintx4* gp = (const uintx4*)s.hbR;
            #pragma unroll
            for (int k = 0; k < 8; ++k) cr[k] = gp[k * 512 + tid];
            #pragma unroll
            for (int k = 0; k < 8; ++k) {
                int row = k * 64 + (tid >> 3);
                *(uintx4*)(hbS + row * 144 + (tid & 7) * 16) = cr[k];
            }
        }
        hja = ((const uintx4*)s.hjR)[j * 8 + q];
        hjb = ((const uintx4*)s.hjR)[j * 8 + 4 + q];
        if (tid < 64)
            hPrevS[tid >> 5][tid & 31] = s.hR[bid * 64 + tid];
        __syncthreads();   // weights + hbS + hPrevS ready
    } else {
        __syncthreads();   // w1tL ready (needed for wbi/wbj below)
        // ---- h = 0: compute hbS rows directly: si(row,cc) = b[row]*wbi[cc] ----
        {
            const int m = tid & 7;
            #pragma unroll
            for (int k = 0; k < 8; ++k) {
                int row = k * 64 + (tid >> 3);
                float bv = s.b[row];
                uintx4 v;
                #pragma unroll
                for (int i = 0; i < 4; ++i) {
                    int cc = m * 8 + 2 * i;
                    v[i] = pkrtz(bv * w1tL[65 * 65 + cc], bv * w1tL[65 * 65 + cc + 1]);
                }
                *(uintx4*)(hbS + row * 144 + m * 16) = v;
            }
        }
        // hj for own 2 nodes: sj = b[jj]*wbj[cc] + mpb1[cc]
        if (tid < 128) {
            int node = tid >> 6, cc = tid & 63;
            int jj = bid * 2 + node;
            float bj = s.b[jj];
            float sj = bj * w1tL[66 * 65 + cc] + s.mpb1[cc];
            float sjp = __shfl(sj, lane ^ 1);
            if (!(cc & 1))
                *(unsigned*)(hjL + node * 128 + (cc >> 1) * 4) = pkrtz(sj, sjp);
        }
        __syncthreads();   // hbS + hjL ready
        hja = *(const uintx4*)(hjL + nsel * 128 + q * 16);
        hjb = *(const uintx4*)(hjL + nsel * 128 + 64 + q * 16);
    }

    float accf[2][4];
    #pragma unroll
    for (int t2 = 0; t2 < 2; ++t2)
        #pragma unroll
        for (int r = 0; r < 4; ++r) accf[t2][r] = 0.0f;

    // ---- 8 edge groups (rolled; R7-verified body) ----
    #pragma unroll 1
    for (int kk = 0; kk < 8; ++kk) {
        const int k4  = kk >> 1;
        const int G   = 8 * k4 + ((kk & 1) ? 4 : 0) + nw;
        const float Jv = __shfl((kk & 1) ? jB : jA, k4 * 16 + c);

        const char* rb = hbS + (G * 16 + c) * 144;
        uintx4 vlo = *(const uintx4*)(rb + q * 16);
        uintx4 vhi = *(const uintx4*)(rb + 64 + q * 16);
        const unsigned Jp = pkrtz(Jv, Jv);

        uintx4 a0u, a1u;
        #pragma unroll
        for (int i = 0; i < 4; ++i) {
            a0u[i] = pk_relu(pk_fma(Jp, wja[i], pk_add(vlo[i], hja[i])));
            a1u[i] = pk_relu(pk_fma(Jp, wjb[i], pk_add(vhi[i], hjb[i])));
        }
        f16x8 B0 = __builtin_bit_cast(f16x8, a0u);
        f16x8 B1 = __builtin_bit_cast(f16x8, a1u);

        floatx4 c1[4];
        #pragma unroll
        for (int t4 = 0; t4 < 4; ++t4) {
            c1[t4] = __builtin_amdgcn_mfma_f32_16x16x32_f16(Aw2[0][t4], B0, b2i[t4], 0, 0, 0);
            c1[t4] = __builtin_amdgcn_mfma_f32_16x16x32_f16(Aw2[1][t4], B1, c1[t4], 0, 0, 0);
        }
        #pragma unroll
        for (int t4 = 0; t4 < 4; ++t4) {
            unsigned p0 = pkrtz(fmaxf(c1[t4][0], 0.f), fmaxf(c1[t4][1], 0.f));
            unsigned p1 = pkrtz(fmaxf(c1[t4][2], 0.f), fmaxf(c1[t4][3], 0.f));
            *(uint2*)(m2Lw + c * 144 + t4 * 32 + q * 8) = make_uint2(p0, p1);
        }
        uintx4 rlo = *(const uintx4*)(m2Lw + c * 144 + q * 16);
        uintx4 rhi = *(const uintx4*)(m2Lw + c * 144 + 64 + q * 16);
        f16x8 B2lo = __builtin_bit_cast(f16x8, rlo);
        f16x8 B2hi = __builtin_bit_cast(f16x8, rhi);

        floatx4 c2[2];
        #pragma unroll
        for (int t2 = 0; t2 < 2; ++t2) {
            c2[t2] = __builtin_amdgcn_mfma_f32_16x16x32_f16(Aw3[0][t2], B2lo, b3i[t2], 0, 0, 0);
            c2[t2] = __builtin_amdgcn_mfma_f32_16x16x32_f16(Aw3[1][t2], B2hi, c2[t2], 0, 0, 0);
        }
        #pragma unroll
        for (int t2 = 0; t2 < 2; ++t2)
            #pragma unroll
            for (int r = 0; r < 4; ++r)
                accf[t2][r] += fmaxf(c2[t2][r], 0.0f);
    }

    #pragma unroll
    for (int m = 1; m < 16; m <<= 1)
        #pragma unroll
        for (int t2 = 0; t2 < 2; ++t2)
            #pragma unroll
            for (int r = 0; r < 4; ++r)
                accf[t2][r] += __shfl_xor(accf[t2][r], m);
    if (c == 0) {
        #pragma unroll
        for (int t2 = 0; t2 < 2; ++t2)
            #pragma unroll
            for (int r = 0; r < 4; ++r)
                msum[wave][t2 * 16 + q * 4 + r] = accf[t2][r];
    }
    __syncthreads();

    if (tid < 64) {
        int node = tid >> 5, d = tid & 31;
        msgS[node][d] = msum[node * 4 + 0][d] + msum[node * 4 + 1][d] +
                        msum[node * 4 + 2][d] + msum[node * 4 + 3][d];
    }
    __syncthreads();

    if (tid < 192) {
        int node = tid / 96, r = tid % 96;
        float a  = s.bih[r];
        float bb = s.bhh[r];
        if (!s.hzero) {
            #pragma unroll
            for (int k = 0; k < 32; ++k) {
                float hv = hPrevS[node][k];
                a  = fmaf(hv, wihL[k * 97 + r], a);
                bb = fmaf(hv, whhL[k * 97 + r], bb);
            }
        }
        #pragma unroll
        for (int k = 0; k < 32; ++k)
            a = fmaf(msgS[node][k], wihL[(32 + k) * 97 + r], a);
        giS[node][r] = a; ghS[node][r] = bb;
    }
    __syncthreads();

    if (tid < 64) {
        int node = tid >> 5, d = tid & 31;
        float r  = sigmoidf_(giS[node][d] + ghS[node][d]);
        float z  = sigmoidf_(giS[node][32 + d] + ghS[node][32 + d]);
        float ng = tanhf(giS[node][64 + d] + r * ghS[node][64 + d]);
        float hold = s.hzero ? 0.0f : hPrevS[node][d];
        float hv = (1.0f - z) * ng + z * hold;
        hS[node][d] = hv;
        s.hW[bid * 64 + tid] = hv;
    }
    __syncthreads();

    if (!s.rdout) {
        // projection for next step: si/sj from new h (w1tL in LDS)
        if (tid < 128) {
            int node = tid >> 6, cc = tid & 63;
            int jj = bid * 2 + node;
            float bj = s.b[jj];
            float si = bj * w1tL[65 * 65 + cc];
            float sj = bj * w1tL[66 * 65 + cc] + s.mpb1[cc];
            #pragma unroll
            for (int d = 0; d < 32; ++d) {
                float hv = hS[node][d];
                si = fmaf(hv, w1tL[d * 65 + cc], si);
                sj = fmaf(hv, w1tL[(32 + d) * 65 + cc], sj);
            }
            float sip = __shfl(si, lane ^ 1);
            float sjp = __shfl(sj, lane ^ 1);
            if (!(cc & 1)) {
                s.hbW[jj * 32 + (cc >> 1)] = pkrtz(si, sip);
                s.hjW[jj * 32 + (cc >> 1)] = pkrtz(sj, sjp);
            }
        }
    } else {
        if (wave < 2) {
            int node = wave;
            int jj = bid * 2 + node;
            float y1 = s.rb1[lane];
            const floatx4* w1p = (const floatx4*)(s.rW1 + lane * 32);
            #pragma unroll
            for (int kk = 0; kk < 8; ++kk) {
                floatx4 v = w1p[kk];
                #pragma unroll
                for (int i = 0; i < 4; ++i)
                    y1 = fmaf(hS[node][kk * 4 + i], v[i], y1);
            }
            y1 = fmaxf(y1, 0.0f);
            float y2 = s.rb2[lane];
            const floatx4* w2p = (const floatx4*)(s.rW2 + lane * 64);
            #pragma unroll
            for (int kk = 0; kk < 16; ++kk) {
                floatx4 v = w2p[kk];
                #pragma unroll
                for (int i = 0; i < 4; ++i)
                    y2 = fmaf(__shfl(y1, kk * 4 + i), v[i], y2);
            }
            y2 = fmaxf(y2, 0.0f);
            float y3 = (lane < 2) ? s.rb3[lane] : 0.0f;
            #pragma unroll
            for (int k = 0; k < 64; ++k) {
                float v = __shfl(y2, k);
                if (lane < 2) y3 = fmaf(v, s.rW3[lane * 64 + k], y3);
            }
            if (lane < 2) s.out[jj * 2 + lane] = sigmoidf_(y3);
        }
    }
}

// ---------------------------------------------------------------------------
extern "C" void kernel_launch(void* const* d_in, const int* in_sizes, int n_in,
                              void* d_out, int out_size, void* d_ws, size_t ws_size,
                              hipStream_t stream)
{
    float* ws = (float*)d_ws;

    const float* J    = (const float*)d_in[0];
    const float* b    = (const float*)d_in[1];
    const float* mpW1 = (const float*)d_in[2];
    const float* mpb1 = (const float*)d_in[3];
    const float* mpW2 = (const float*)d_in[4];
    const float* mpb2 = (const float*)d_in[5];
    const float* mpW3 = (const float*)d_in[6];
    const float* mpb3 = (const float*)d_in[7];
    const float* Wih  = (const float*)d_in[8];
    const float* Whh  = (const float*)d_in[9];
    const float* bih  = (const float*)d_in[10];
    const float* bhh  = (const float*)d_in[11];
    const float* rW1  = (const float*)d_in[12];
    const float* rb1  = (const float*)d_in[13];
    const float* rW2  = (const float*)d_in[14];
    const float* rb2  = (const float*)d_in[15];
    const float* rW3  = (const float*)d_in[16];
    const float* rb3  = (const float*)d_in[17];

    // ping-pong exchange buffers (8 MB into workspace)
    unsigned* hb0 = (unsigned*)(ws + 2097152);            // 16384 dwords
    unsigned* hb1 = hb0 + 16384;
    unsigned* hj0 = hb1 + 16384;
    unsigned* hj1 = hj0 + 16384;
    float*    h0  = (float*)(hj1 + 16384);                // 16384 floats
    float*    h1  = h0 + 16384;

    (void)hipFuncSetAttribute((const void*)step7_kernel,
                              hipFuncAttributeMaxDynamicSharedMemorySize, LDS_TOTAL);

    SParams s;
    s.J = J; s.b = b; s.mpW1 = mpW1; s.mpb1 = mpb1; s.mpW2 = mpW2;
    s.mpb2 = mpb2; s.mpW3 = mpW3; s.mpb3 = mpb3;
    s.Wih = Wih; s.Whh = Whh; s.bih = bih; s.bhh = bhh;
    s.rW1 = rW1; s.rb1 = rb1; s.rW2 = rW2; s.rb2 = rb2; s.rW3 = rW3; s.rb3 = rb3;
    s.out = (float*)d_out;

    for (int t = 0; t < 5; ++t) {
        s.hbR = (t & 1) ? hb0 : hb1;   // read buffer written by previous step
        s.hbW = (t & 1) ? hb1 : hb0;   // t==0 writes hb0? no: see mapping below
        // mapping: t writes X, t+1 reads X. Use parity of t for write target.
        s.hbW = (t & 1) ? hb1 : hb0;
        s.hbR = (t & 1) ? hb0 : hb1;
        s.hjW = (t & 1) ? hj1 : hj0;
        s.hjR = (t & 1) ? hj0 : hj1;
        s.hW  = (t & 1) ? h1 : h0;
        s.hR  = (t & 1) ? h0 : h1;
        s.hzero = (t == 0);
        s.rdout = (t == 4);
        step7_kernel<<<dim3(NB), dim3(512), LDS_TOTAL, stream>>>(s);
    }
}

// Round 9
// 168.696 us; speedup vs baseline: 1.9349x; 1.0968x over previous
//
#include <hip/hip_runtime.h>
#include <math.h>

#define NN 512
#define SD 32
#define HM 64
#define NB 256

typedef _Float16 f16x8 __attribute__((ext_vector_type(8)));
typedef float floatx4 __attribute__((ext_vector_type(4)));
typedef unsigned uintx4 __attribute__((ext_vector_type(4)));

// ---- dynamic LDS layout (bytes) ----
#define OFF_HBS   0        // 512 rows x 144 B packed-f16 hip        = 73728
#define OFF_M2L   73728    // 8 waves x 2304 B (d0 reuses as JT tile scratch)
#define OFF_MSUM  92160    // 8x32 f32
#define OFF_HPREV 93184    // 2x32 f32
#define OFF_HS    93440    // 2x32 f32
#define OFF_MSG   93696    // 2x32 f32
#define OFF_GI    93952    // 2x96 f32
#define OFF_GH    94720    // 2x96 f32
#define OFF_HJ    95488    // 2 nodes x 128 B packed-f16 hj          = 256
#define OFF_W1T   95744    // 67x65 f32 (pad 65)                     = 17420
#define OFF_WIH   113168   // 64x97 f32 ([k][r], pad 97)             = 24832
#define OFF_WHH   138000   // 32x97 f32 ([k][r], pad 97)             = 12416
#define LDS_TOTAL 150416   // < 160 KiB/CU

__device__ __forceinline__ float sigmoidf_(float x) {
    return 1.0f / (1.0f + __expf(-x));
}
__device__ __forceinline__ unsigned pkrtz(float a, float b) {
    unsigned r;
    asm("v_cvt_pkrtz_f16_f32 %0, %1, %2" : "=v"(r) : "v"(a), "v"(b));
    return r;
}
__device__ __forceinline__ unsigned pk_add(unsigned a, unsigned b) {
    unsigned r;
    asm("v_pk_add_f16 %0, %1, %2" : "=v"(r) : "v"(a), "v"(b));
    return r;
}
__device__ __forceinline__ unsigned pk_fma(unsigned a, unsigned b, unsigned c) {
    unsigned r;
    asm("v_pk_fma_f16 %0, %1, %2, %3" : "=v"(r) : "v"(a), "v"(b), "v"(c));
    return r;
}
__device__ __forceinline__ unsigned pk_relu(unsigned a) {
    unsigned r, z = 0u;
    asm("v_pk_max_f16 %0, %1, %2" : "=v"(r) : "v"(a), "v"(z));
    return r;
}

// ===========================================================================
// 5-dispatch pipeline. Dispatch 0 = step 0 + prep: it pays the strided
// gathers anyway for its own compute, and additionally (a) transposes its
// 32x32 J tile into JT (LDS-tile, coalesced both ways), (b) block 0/wave 0
// stores its in-register MFMA fragments as the prepacked arrays. Dispatches
// 1-4 read prepacked fragments (16 B/lane coalesced) + JT rows — the
// R1-verified fast path (R8 redid the gathers every dispatch: +9 us each).
// Cross-step exchange: plain cached global I/O; dispatch-boundary coherence.
// ===========================================================================
struct SParams {
    const float *J, *b, *mpW1, *mpb1, *mpW2, *mpb2, *mpW3, *mpb3;
    const float *Wih, *Whh, *bih, *bhh;
    const float *rW1, *rb1, *rW2, *rb2, *rW3, *rb3;
    float *JT;                       // 512x512 f32 (written by d0)
    unsigned *w2p, *w3p, *wjp;       // prepacked fragments (written by d0)
    const unsigned *hbR; unsigned *hbW;
    const unsigned *hjR; unsigned *hjW;
    const float *hR;     float *hW;
    float *out;
    int hzero, rdout;
};

__global__ __launch_bounds__(512, 1) void step8_kernel(SParams s)
{
    extern __shared__ __align__(16) char smem[];
    const int tid  = threadIdx.x;
    const int bid  = blockIdx.x;
    const int lane = tid & 63;
    const int wave = tid >> 6;
    const int nsel = wave >> 2;
    const int nw   = wave & 3;
    const int j    = bid * 2 + nsel;
    const int q    = lane >> 4;
    const int c    = lane & 15;

    char* hbS = smem + OFF_HBS;
    float (*msum)[32]   = (float(*)[32])(smem + OFF_MSUM);
    float (*hPrevS)[32] = (float(*)[32])(smem + OFF_HPREV);
    float (*hS)[32]     = (float(*)[32])(smem + OFF_HS);
    float (*msgS)[32]   = (float(*)[32])(smem + OFF_MSG);
    float (*giS)[96]    = (float(*)[96])(smem + OFF_GI);
    float (*ghS)[96]    = (float(*)[96])(smem + OFF_GH);
    char*  hjL  = smem + OFF_HJ;
    float* w1tL = (float*)(smem + OFF_W1T);   // [d=0..66][cc], pitch 65
    float* wihL = (float*)(smem + OFF_WIH);   // [k=0..63][r], pitch 97
    float* whhL = (float*)(smem + OFF_WHH);   // [k=0..31][r], pitch 97
    char*  m2Lw = smem + OFF_M2L + wave * 2304;

    // ---- per-dispatch: stage weights into padded LDS (coalesced) ----
    for (int n = tid; n < 64 * 67; n += 512) {
        int cc = n / 67, d = n % 67;
        w1tL[d * 65 + cc] = s.mpW1[n];
    }
    for (int n = tid; n < 96 * 64; n += 512)
        wihL[(n & 63) * 97 + (n >> 6)] = s.Wih[n];
    for (int n = tid; n < 96 * 32; n += 512)
        whhL[(n & 31) * 97 + (n >> 5)] = s.Whh[n];

    floatx4 b2i[4], b3i[2];
    #pragma unroll
    for (int t4 = 0; t4 < 4; ++t4)
        #pragma unroll
        for (int r = 0; r < 4; ++r) b2i[t4][r] = s.mpb2[t4 * 16 + q * 4 + r];
    #pragma unroll
    for (int t2 = 0; t2 < 2; ++t2)
        #pragma unroll
        for (int r = 0; r < 4; ++r) b3i[t2][r] = s.mpb3[t2 * 16 + q * 4 + r];

    f16x8 Aw2[2][4], Aw3[2][2];
    uintx4 wja, wjb;
    float jA, jB;
    uintx4 hja, hjb;

    if (s.hzero) {
        // ==== dispatch 0: gathers from raw inputs + prep products ====
        // JT tile transpose (write phase) into m2L scratch
        float (*tile)[33] = (float(*)[33])(smem + OFF_M2L);
        const int bx = bid & 15, by = bid >> 4;
        const int tx = tid & 31, ty = tid >> 5;   // ty in 0..15
        #pragma unroll
        for (int r = 0; r < 32; r += 16)
            tile[ty + r][tx] = s.J[(by * 32 + ty + r) * NN + bx * 32 + tx];

        // fragment gathers (strided, one-time)
        #pragma unroll
        for (int f = 0; f < 2; ++f)
            #pragma unroll
            for (int t4 = 0; t4 < 4; ++t4) {
                const float* src = s.mpW2 + (t4 * 16 + c) * 64 + f * 32 + q * 8;
                floatx4 s0 = *(const floatx4*)(src);
                floatx4 s1 = *(const floatx4*)(src + 4);
                uintx4 u;
                u[0] = pkrtz(s0[0], s0[1]); u[1] = pkrtz(s0[2], s0[3]);
                u[2] = pkrtz(s1[0], s1[1]); u[3] = pkrtz(s1[2], s1[3]);
                Aw2[f][t4] = __builtin_bit_cast(f16x8, u);
            }
        #pragma unroll
        for (int f = 0; f < 2; ++f)
            #pragma unroll
            for (int t2 = 0; t2 < 2; ++t2) {
                const float* src = s.mpW3 + (t2 * 16 + c) * 64 + f * 32 + q * 8;
                floatx4 s0 = *(const floatx4*)(src);
                floatx4 s1 = *(const floatx4*)(src + 4);
                uintx4 u;
                u[0] = pkrtz(s0[0], s0[1]); u[1] = pkrtz(s0[2], s0[3]);
                u[2] = pkrtz(s1[0], s1[1]); u[3] = pkrtz(s1[2], s1[3]);
                Aw3[f][t2] = __builtin_bit_cast(f16x8, u);
            }
        #pragma unroll
        for (int i = 0; i < 4; ++i) {
            int r0 = q * 8 + 2 * i;
            wja[i] = pkrtz(s.mpW1[r0 * 67 + 64], s.mpW1[(r0 + 1) * 67 + 64]);
            int r1 = r0 + 32;
            wjb[i] = pkrtz(s.mpW1[r1 * 67 + 64], s.mpW1[(r1 + 1) * 67 + 64]);
        }
        // J column j direct gather (one-time)
        jA = s.J[((8 * q + nw) * 16 + c) * NN + j];
        jB = s.J[((8 * q + 4 + nw) * 16 + c) * NN + j];

        __syncthreads();   // w1tL + tile ready

        // JT store (read phase, coalesced)
        #pragma unroll
        for (int r = 0; r < 32; r += 16)
            s.JT[(bx * 32 + ty + r) * NN + by * 32 + tx] = tile[tx][ty + r];

        // prepacked-fragment write (layout == step read layout, by construction)
        if (bid == 0 && wave == 0) {
            #pragma unroll
            for (int f = 0; f < 2; ++f)
                #pragma unroll
                for (int t4 = 0; t4 < 4; ++t4)
                    ((uintx4*)s.w2p)[(f * 4 + t4) * 64 + lane] =
                        __builtin_bit_cast(uintx4, Aw2[f][t4]);
            #pragma unroll
            for (int f = 0; f < 2; ++f)
                #pragma unroll
                for (int t2 = 0; t2 < 2; ++t2)
                    ((uintx4*)s.w3p)[(f * 2 + t2) * 64 + lane] =
                        __builtin_bit_cast(uintx4, Aw3[f][t2]);
            ((uintx4*)s.wjp)[lane] = wja;
            ((uintx4*)s.wjp)[64 + lane] = wjb;
        }

        // h = 0: compute hbS rows directly: si(row,cc) = b[row]*wbi[cc]
        {
            const int m = tid & 7;
            #pragma unroll
            for (int k = 0; k < 8; ++k) {
                int row = k * 64 + (tid >> 3);
                float bv = s.b[row];
                uintx4 v;
                #pragma unroll
                for (int i = 0; i < 4; ++i) {
                    int cc = m * 8 + 2 * i;
                    v[i] = pkrtz(bv * w1tL[65 * 65 + cc], bv * w1tL[65 * 65 + cc + 1]);
                }
                *(uintx4*)(hbS + row * 144 + m * 16) = v;
            }
        }
        // hj for own 2 nodes: sj = b[jj]*wbj[cc] + mpb1[cc]
        if (tid < 128) {
            int node = tid >> 6, cc = tid & 63;
            int jj = bid * 2 + node;
            float bj = s.b[jj];
            float sj = bj * w1tL[66 * 65 + cc] + s.mpb1[cc];
            float sjp = __shfl(sj, lane ^ 1);
            if (!(cc & 1))
                *(unsigned*)(hjL + node * 128 + (cc >> 1) * 4) = pkrtz(sj, sjp);
        }
        __syncthreads();   // hbS + hjL ready (also fences tile before m2Lw reuse)
        hja = *(const uintx4*)(hjL + nsel * 128 + q * 16);
        hjb = *(const uintx4*)(hjL + nsel * 128 + 64 + q * 16);
    } else {
        // ==== dispatches 1-4: coalesced prepacked reads (R1 fast path) ====
        #pragma unroll
        for (int f = 0; f < 2; ++f)
            #pragma unroll
            for (int t4 = 0; t4 < 4; ++t4)
                Aw2[f][t4] = __builtin_bit_cast(f16x8,
                    ((const uintx4*)s.w2p)[(f * 4 + t4) * 64 + lane]);
        #pragma unroll
        for (int f = 0; f < 2; ++f)
            #pragma unroll
            for (int t2 = 0; t2 < 2; ++t2)
                Aw3[f][t2] = __builtin_bit_cast(f16x8,
                    ((const uintx4*)s.w3p)[(f * 2 + t2) * 64 + lane]);
        wja = ((const uintx4*)s.wjp)[lane];
        wjb = ((const uintx4*)s.wjp)[64 + lane];
        jA = s.JT[j * NN + (8 * q + nw) * 16 + c];
        jB = s.JT[j * NN + (8 * q + 4 + nw) * 16 + c];

        // stage hb (64 KB) -> LDS via plain cached loads
        {
            uintx4 cr[8];
            const uintx4* gp = (const uintx4*)s.hbR;
            #pragma unroll
            for (int k = 0; k < 8; ++k) cr[k] = gp[k * 512 + tid];
            #pragma unroll
            for (int k = 0; k < 8; ++k) {
                int row = k * 64 + (tid >> 3);
                *(uintx4*)(hbS + row * 144 + (tid & 7) * 16) = cr[k];
            }
        }
        hja = ((const uintx4*)s.hjR)[j * 8 + q];
        hjb = ((const uintx4*)s.hjR)[j * 8 + 4 + q];
        if (tid < 64)
            hPrevS[tid >> 5][tid & 31] = s.hR[bid * 64 + tid];
        __syncthreads();   // weights + hbS + hPrevS ready
    }

    float accf[2][4];
    #pragma unroll
    for (int t2 = 0; t2 < 2; ++t2)
        #pragma unroll
        for (int r = 0; r < 4; ++r) accf[t2][r] = 0.0f;

    // ---- 8 edge groups (rolled; R7/R8-verified body) ----
    #pragma unroll 1
    for (int kk = 0; kk < 8; ++kk) {
        const int k4  = kk >> 1;
        const int G   = 8 * k4 + ((kk & 1) ? 4 : 0) + nw;
        const float Jv = __shfl((kk & 1) ? jB : jA, k4 * 16 + c);

        const char* rb = hbS + (G * 16 + c) * 144;
        uintx4 vlo = *(const uintx4*)(rb + q * 16);
        uintx4 vhi = *(const uintx4*)(rb + 64 + q * 16);
        const unsigned Jp = pkrtz(Jv, Jv);

        uintx4 a0u, a1u;
        #pragma unroll
        for (int i = 0; i < 4; ++i) {
            a0u[i] = pk_relu(pk_fma(Jp, wja[i], pk_add(vlo[i], hja[i])));
            a1u[i] = pk_relu(pk_fma(Jp, wjb[i], pk_add(vhi[i], hjb[i])));
        }
        f16x8 B0 = __builtin_bit_cast(f16x8, a0u);
        f16x8 B1 = __builtin_bit_cast(f16x8, a1u);

        floatx4 c1[4];
        #pragma unroll
        for (int t4 = 0; t4 < 4; ++t4) {
            c1[t4] = __builtin_amdgcn_mfma_f32_16x16x32_f16(Aw2[0][t4], B0, b2i[t4], 0, 0, 0);
            c1[t4] = __builtin_amdgcn_mfma_f32_16x16x32_f16(Aw2[1][t4], B1, c1[t4], 0, 0, 0);
        }
        #pragma unroll
        for (int t4 = 0; t4 < 4; ++t4) {
            unsigned p0 = pkrtz(fmaxf(c1[t4][0], 0.f), fmaxf(c1[t4][1], 0.f));
            unsigned p1 = pkrtz(fmaxf(c1[t4][2], 0.f), fmaxf(c1[t4][3], 0.f));
            *(uint2*)(m2Lw + c * 144 + t4 * 32 + q * 8) = make_uint2(p0, p1);
        }
        uintx4 rlo = *(const uintx4*)(m2Lw + c * 144 + q * 16);
        uintx4 rhi = *(const uintx4*)(m2Lw + c * 144 + 64 + q * 16);
        f16x8 B2lo = __builtin_bit_cast(f16x8, rlo);
        f16x8 B2hi = __builtin_bit_cast(f16x8, rhi);

        floatx4 c2[2];
        #pragma unroll
        for (int t2 = 0; t2 < 2; ++t2) {
            c2[t2] = __builtin_amdgcn_mfma_f32_16x16x32_f16(Aw3[0][t2], B2lo, b3i[t2], 0, 0, 0);
            c2[t2] = __builtin_amdgcn_mfma_f32_16x16x32_f16(Aw3[1][t2], B2hi, c2[t2], 0, 0, 0);
        }
        #pragma unroll
        for (int t2 = 0; t2 < 2; ++t2)
            #pragma unroll
            for (int r = 0; r < 4; ++r)
                accf[t2][r] += fmaxf(c2[t2][r], 0.0f);
    }

    #pragma unroll
    for (int m = 1; m < 16; m <<= 1)
        #pragma unroll
        for (int t2 = 0; t2 < 2; ++t2)
            #pragma unroll
            for (int r = 0; r < 4; ++r)
                accf[t2][r] += __shfl_xor(accf[t2][r], m);
    if (c == 0) {
        #pragma unroll
        for (int t2 = 0; t2 < 2; ++t2)
            #pragma unroll
            for (int r = 0; r < 4; ++r)
                msum[wave][t2 * 16 + q * 4 + r] = accf[t2][r];
    }
    __syncthreads();

    if (tid < 64) {
        int node = tid >> 5, d = tid & 31;
        msgS[node][d] = msum[node * 4 + 0][d] + msum[node * 4 + 1][d] +
                        msum[node * 4 + 2][d] + msum[node * 4 + 3][d];
    }
    __syncthreads();

    if (tid < 192) {
        int node = tid / 96, r = tid % 96;
        float a  = s.bih[r];
        float bb = s.bhh[r];
        if (!s.hzero) {
            #pragma unroll
            for (int k = 0; k < 32; ++k) {
                float hv = hPrevS[node][k];
                a  = fmaf(hv, wihL[k * 97 + r], a);
                bb = fmaf(hv, whhL[k * 97 + r], bb);
            }
        }
        #pragma unroll
        for (int k = 0; k < 32; ++k)
            a = fmaf(msgS[node][k], wihL[(32 + k) * 97 + r], a);
        giS[node][r] = a; ghS[node][r] = bb;
    }
    __syncthreads();

    if (tid < 64) {
        int node = tid >> 5, d = tid & 31;
        float r  = sigmoidf_(giS[node][d] + ghS[node][d]);
        float z  = sigmoidf_(giS[node][32 + d] + ghS[node][32 + d]);
        float ng = tanhf(giS[node][64 + d] + r * ghS[node][64 + d]);
        float hold = s.hzero ? 0.0f : hPrevS[node][d];
        float hv = (1.0f - z) * ng + z * hold;
        hS[node][d] = hv;
        s.hW[bid * 64 + tid] = hv;
    }
    __syncthreads();

    if (!s.rdout) {
        // projection for next step (w1tL in LDS)
        if (tid < 128) {
            int node = tid >> 6, cc = tid & 63;
            int jj = bid * 2 + node;
            float bj = s.b[jj];
            float si = bj * w1tL[65 * 65 + cc];
            float sj = bj * w1tL[66 * 65 + cc] + s.mpb1[cc];
            #pragma unroll
            for (int d = 0; d < 32; ++d) {
                float hv = hS[node][d];
                si = fmaf(hv, w1tL[d * 65 + cc], si);
                sj = fmaf(hv, w1tL[(32 + d) * 65 + cc], sj);
            }
            float sip = __shfl(si, lane ^ 1);
            float sjp = __shfl(sj, lane ^ 1);
            if (!(cc & 1)) {
                s.hbW[jj * 32 + (cc >> 1)] = pkrtz(si, sip);
                s.hjW[jj * 32 + (cc >> 1)] = pkrtz(sj, sjp);
            }
        }
    } else {
        if (wave < 2) {
            int node = wave;
            int jj = bid * 2 + node;
            float y1 = s.rb1[lane];
            const floatx4* w1p = (const floatx4*)(s.rW1 + lane * 32);
            #pragma unroll
            for (int kk = 0; kk < 8; ++kk) {
                floatx4 v = w1p[kk];
                #pragma unroll
                for (int i = 0; i < 4; ++i)
                    y1 = fmaf(hS[node][kk * 4 + i], v[i], y1);
            }
            y1 = fmaxf(y1, 0.0f);
            float y2 = s.rb2[lane];
            const floatx4* w2p = (const floatx4*)(s.rW2 + lane * 64);
            #pragma unroll
            for (int kk = 0; kk < 16; ++kk) {
                floatx4 v = w2p[kk];
                #pragma unroll
                for (int i = 0; i < 4; ++i)
                    y2 = fmaf(__shfl(y1, kk * 4 + i), v[i], y2);
            }
            y2 = fmaxf(y2, 0.0f);
            float y3 = (lane < 2) ? s.rb3[lane] : 0.0f;
            #pragma unroll
            for (int k = 0; k < 64; ++k) {
                float v = __shfl(y2, k);
                if (lane < 2) y3 = fmaf(v, s.rW3[lane * 64 + k], y3);
            }
            if (lane < 2) s.out[jj * 2 + lane] = sigmoidf_(y3);
        }
    }
}

// ---------------------------------------------------------------------------
extern "C" void kernel_launch(void* const* d_in, const int* in_sizes, int n_in,
                              void* d_out, int out_size, void* d_ws, size_t ws_size,
                              hipStream_t stream)
{
    float* ws = (float*)d_ws;

    const float* J    = (const float*)d_in[0];
    const float* b    = (const float*)d_in[1];
    const float* mpW1 = (const float*)d_in[2];
    const float* mpb1 = (const float*)d_in[3];
    const float* mpW2 = (const float*)d_in[4];
    const float* mpb2 = (const float*)d_in[5];
    const float* mpW3 = (const float*)d_in[6];
    const float* mpb3 = (const float*)d_in[7];
    const float* Wih  = (const float*)d_in[8];
    const float* Whh  = (const float*)d_in[9];
    const float* bih  = (const float*)d_in[10];
    const float* bhh  = (const float*)d_in[11];
    const float* rW1  = (const float*)d_in[12];
    const float* rb1  = (const float*)d_in[13];
    const float* rW2  = (const float*)d_in[14];
    const float* rb2  = (const float*)d_in[15];
    const float* rW3  = (const float*)d_in[16];
    const float* rb3  = (const float*)d_in[17];

    // prep products at workspace base
    float*    JT  = ws;                         // 262144 floats (1 MB)
    unsigned* w2p = (unsigned*)(ws + 262144);   // 2048 dwords
    unsigned* w3p = w2p + 2048;                 // 1024
    unsigned* wjp = w3p + 1024;                 // 512

    // ping-pong exchange buffers (8 MB into workspace)
    unsigned* hb0 = (unsigned*)(ws + 2097152);  // 16384 dwords each
    unsigned* hb1 = hb0 + 16384;
    unsigned* hj0 = hb1 + 16384;
    unsigned* hj1 = hj0 + 16384;
    float*    h0  = (float*)(hj1 + 16384);
    float*    h1  = h0 + 16384;

    (void)hipFuncSetAttribute((const void*)step8_kernel,
                              hipFuncAttributeMaxDynamicSharedMemorySize, LDS_TOTAL);

    SParams s;
    s.J = J; s.b = b; s.mpW1 = mpW1; s.mpb1 = mpb1; s.mpW2 = mpW2;
    s.mpb2 = mpb2; s.mpW3 = mpW3; s.mpb3 = mpb3;
    s.Wih = Wih; s.Whh = Whh; s.bih = bih; s.bhh = bhh;
    s.rW1 = rW1; s.rb1 = rb1; s.rW2 = rW2; s.rb2 = rb2; s.rW3 = rW3; s.rb3 = rb3;
    s.JT = JT; s.w2p = w2p; s.w3p = w3p; s.wjp = wjp;
    s.out = (float*)d_out;

    for (int t = 0; t < 5; ++t) {
        // step t writes (t even ? hb0 : hb1); step t+1 reads it
        s.hbW = (t & 1) ? hb1 : hb0;
        s.hbR = (t & 1) ? hb0 : hb1;
        s.hjW = (t & 1) ? hj1 : hj0;
        s.hjR = (t & 1) ? hj0 : hj1;
        s.hW  = (t & 1) ? h1 : h0;
        s.hR  = (t & 1) ? h0 : h1;
        s.hzero = (t == 0);
        s.rdout = (t == 4);
        step8_kernel<<<dim3(NB), dim3(512), LDS_TOTAL, stream>>>(s);
    }
}